// Round 2
// baseline (600.060 us; speedup 1.0000x reference)
//
#include <hip/hip_runtime.h>

#define TLEN 4096
#define NROWS 16384      // B*C = 16*1024
#define VEC_PER_ROW 1024 // TLEN/4

typedef float floatx4 __attribute__((ext_vector_type(4)));  // native vector: nt-store accepts it

// One block per row (4096 floats). 256 threads, each producing 16 contiguous
// outputs (4 float4) from 6 float4 loads (register halo). Softmax of the 7
// taps is computed once per thread but amortized over 16 outputs.
__global__ __launch_bounds__(256) void lconv7_kernel(const float* __restrict__ x,
                                                     const float* __restrict__ wraw,
                                                     float* __restrict__ out) {
    const int row = blockIdx.x;      // [0, 16384)
    const int tid = threadIdx.x;     // [0, 256)
    const int h   = row & 15;        // head = c % 16

    // --- softmax over the 7 taps (wave-uniform; scalar loads + cheap VALU) ---
    float w[7];
    float m = -1e30f;
#pragma unroll
    for (int k = 0; k < 7; ++k) {
        w[k] = wraw[h * 7 + k];
        m = fmaxf(m, w[k]);
    }
    float s = 0.0f;
#pragma unroll
    for (int k = 0; k < 7; ++k) {
        w[k] = __expf(w[k] - m);
        s += w[k];
    }
    const float inv = __frcp_rn(s);
#pragma unroll
    for (int k = 0; k < 7; ++k) w[k] *= inv;

    // --- load 6 float4: left halo, 4 main vecs, right halo ---
    const size_t base = (size_t)row * TLEN;
    const float4* rowv = (const float4*)(x + base);
    const int v0 = tid * 4;          // first main vec index [0, 1024) step 4

    const float4 Z = make_float4(0.f, 0.f, 0.f, 0.f);
    float4 L  = (tid > 0)   ? rowv[v0 - 1] : Z;   // x[16t-4 .. 16t-1]
    float4 A0 = rowv[v0 + 0];
    float4 A1 = rowv[v0 + 1];
    float4 A2 = rowv[v0 + 2];
    float4 A3 = rowv[v0 + 3];
    float4 R  = (tid < 255) ? rowv[v0 + 4] : Z;   // x[16t+16 .. 16t+19]

    // xin[p] = x[16*tid - 4 + p], p in [0, 24)
    float xin[24] = {L.x,  L.y,  L.z,  L.w,
                     A0.x, A0.y, A0.z, A0.w,
                     A1.x, A1.y, A1.z, A1.w,
                     A2.x, A2.y, A2.z, A2.w,
                     A3.x, A3.y, A3.z, A3.w,
                     R.x,  R.y,  R.z,  R.w};

    // out[16t + 4j + i] = sum_k w[k] * x[16t + 4j + i + k - 3]
    //                   = sum_k w[k] * xin[4j + i + k + 1]
    floatx4 o[4];
#pragma unroll
    for (int j = 0; j < 4; ++j) {
#pragma unroll
        for (int i = 0; i < 4; ++i) {
            float acc = 0.0f;
#pragma unroll
            for (int k = 0; k < 7; ++k) acc = fmaf(w[k], xin[4 * j + i + k + 1], acc);
            o[j][i] = acc;
        }
    }

    // Output is write-once, never re-read: nontemporal stores skip cache
    // allocation so L2/L3 stay available for the read stream.
    floatx4* ov = (floatx4*)(out + base);
#pragma unroll
    for (int j = 0; j < 4; ++j) {
        __builtin_nontemporal_store(o[j], &ov[v0 + j]);
    }
}

extern "C" void kernel_launch(void* const* d_in, const int* in_sizes, int n_in,
                              void* d_out, int out_size, void* d_ws, size_t ws_size,
                              hipStream_t stream) {
    const float* x    = (const float*)d_in[0];   // (16,1024,4096) fp32
    const float* wgt  = (const float*)d_in[1];   // (16,1,7) fp32
    float*       outp = (float*)d_out;           // (16,1024,4096) fp32

    lconv7_kernel<<<NROWS, 256, 0, stream>>>(x, wgt, outp);
}

// Round 4
// 454.869 us; speedup vs baseline: 1.3192x; 1.3192x over previous
//
#include <hip/hip_runtime.h>

#define TLEN 4096
#define NROWS 16384      // B*C = 16*1024
#define VEC_PER_ROW 1024 // TLEN/4
#define SEGS 4           // each thread: vecs tid + s*256, s in [0,4)

// One block per row. 256 threads; thread t handles the 4 INTERLEAVED vector
// positions {t, t+256, t+512, t+768} so every load/store instruction is
// wave-contiguous (16B lane stride -> 1KB per instruction). Softmax of the 7
// taps is computed once per thread, amortized over 16 outputs; 12 loads are
// issued up-front for deep memory-level parallelism.
__global__ __launch_bounds__(256) void lconv7_kernel(const float* __restrict__ x,
                                                     const float* __restrict__ wraw,
                                                     float* __restrict__ out) {
    const int row = blockIdx.x;      // [0, 16384)
    const int tid = threadIdx.x;     // [0, 256)
    const int h   = row & 15;        // head = c % 16

    const size_t base = (size_t)row * TLEN;
    const float4* rowv = (const float4*)(x + base);
    const float4 Z = make_float4(0.f, 0.f, 0.f, 0.f);

    // --- issue all 12 loads first (3 per segment, all wave-contiguous) ---
    float4 L[SEGS], M[SEGS], R[SEGS];
#pragma unroll
    for (int s = 0; s < SEGS; ++s) {
        const int v = s * 256 + tid;                 // [0, 1024)
        L[s] = (v > 0)               ? rowv[v - 1] : Z;
        M[s] = rowv[v];
        R[s] = (v < VEC_PER_ROW - 1) ? rowv[v + 1] : Z;
    }

    // --- softmax over the 7 taps (overlaps with the loads in flight) ---
    float w[7];
    float m = -1e30f;
#pragma unroll
    for (int k = 0; k < 7; ++k) {
        w[k] = wraw[h * 7 + k];
        m = fmaxf(m, w[k]);
    }
    float s0 = 0.0f;
#pragma unroll
    for (int k = 0; k < 7; ++k) {
        w[k] = __expf(w[k] - m);
        s0 += w[k];
    }
    const float inv = __frcp_rn(s0);
#pragma unroll
    for (int k = 0; k < 7; ++k) w[k] *= inv;

    // --- compute + store per segment ---
#pragma unroll
    for (int s = 0; s < SEGS; ++s) {
        const int v = s * 256 + tid;
        float xa[12] = {L[s].x, L[s].y, L[s].z, L[s].w,
                        M[s].x, M[s].y, M[s].z, M[s].w,
                        R[s].x, R[s].y, R[s].z, R[s].w};
        // out[4v + j] = sum_k w[k] * x[4v + j + k - 3] = sum_k w[k] * xa[j+k+1]
        float4 o;
        float* op = &o.x;
#pragma unroll
        for (int j = 0; j < 4; ++j) {
            float acc = 0.0f;
#pragma unroll
            for (int k = 0; k < 7; ++k) acc = fmaf(w[k], xa[j + k + 1], acc);
            op[j] = acc;
        }
        ((float4*)(out + base))[v] = o;   // wave-contiguous store
    }
}

extern "C" void kernel_launch(void* const* d_in, const int* in_sizes, int n_in,
                              void* d_out, int out_size, void* d_ws, size_t ws_size,
                              hipStream_t stream) {
    const float* x    = (const float*)d_in[0];   // (16,1024,4096) fp32
    const float* wgt  = (const float*)d_in[1];   // (16,1,7) fp32
    float*       outp = (float*)d_out;           // (16,1024,4096) fp32

    lconv7_kernel<<<NROWS, 256, 0, stream>>>(x, wgt, outp);
}